// Round 3
// baseline (127.233 us; speedup 1.0000x reference)
//
#include <hip/hip_runtime.h>
#include <math.h>

#define BB 16
#define TT 2048
#define FF 512

#define CHUNK  32              // t-positions per K1 block
#define NCHUNK (TT / CHUNK)    // 64 flag words per batch

#define ACTIVE_UNITS 4096      // 256 units/batch x 16, 4 waves/unit, rows j<1024
#define ZERO_UNITS   1024      // rows j in [1024,2048): always zero (counts <= 1024)
#define MASK_UNITS   32

typedef float v4f __attribute__((ext_vector_type(4)));

// K1: one block = 32 contiguous t of one batch (+2 halo rows recomputed by the
// edge waves, loads issued in the same batch as the main rows). launch_bounds
// (256,4) -> up to 128 VGPRs so all 18 dwordx4-pairs can be in flight at once.
__global__ __launch_bounds__(256, 4) void wtflag_kernel(const float* __restrict__ x,
                                                        const float* __restrict__ w,
                                                        const float* __restrict__ bias,
                                                        float* __restrict__ wt,
                                                        unsigned int* __restrict__ flags) {
    __shared__ float arr[CHUNK + 2];   // [0]=left halo, [1..32]=chunk, [33]=right halo
    int blk  = blockIdx.x;             // 16*64 = 1024 blocks
    int b    = blk >> 6;
    int c    = blk & 63;
    int t0   = c * CHUNK;
    int tid  = threadIdx.x;
    int wv   = tid >> 6;
    int lane = tid & 63;

    const float* wp = w + lane * 8;
    float4 w0 = *(const float4*)wp;
    float4 w1 = *(const float4*)(wp + 4);
    float bz = bias[0];

    int rbase = b * TT + t0 + wv * 8;
    const float* xr0 = x + (size_t)rbase * FF + lane * 8;

    // halo row: wave0 -> t0-1, wave3 -> t0+CHUNK; others load a dummy (L1-hot) row
    bool halo0 = (wv == 0) && (t0 > 0);
    bool halo3 = (wv == 3) && (t0 + CHUNK < TT);
    int hrow = halo0 ? (b * TT + t0 - 1)
             : (halo3 ? (b * TT + t0 + CHUNK) : rbase);
    const float* xh = x + (size_t)hrow * FF + lane * 8;

    // ---- issue ALL loads first (explicit named regs -> full MLP) ----
    float4 a00 = *(const float4*)(xr0 + 0 * FF), a01 = *(const float4*)(xr0 + 0 * FF + 4);
    float4 a10 = *(const float4*)(xr0 + 1 * FF), a11 = *(const float4*)(xr0 + 1 * FF + 4);
    float4 a20 = *(const float4*)(xr0 + 2 * FF), a21 = *(const float4*)(xr0 + 2 * FF + 4);
    float4 a30 = *(const float4*)(xr0 + 3 * FF), a31 = *(const float4*)(xr0 + 3 * FF + 4);
    float4 a40 = *(const float4*)(xr0 + 4 * FF), a41 = *(const float4*)(xr0 + 4 * FF + 4);
    float4 a50 = *(const float4*)(xr0 + 5 * FF), a51 = *(const float4*)(xr0 + 5 * FF + 4);
    float4 a60 = *(const float4*)(xr0 + 6 * FF), a61 = *(const float4*)(xr0 + 6 * FF + 4);
    float4 a70 = *(const float4*)(xr0 + 7 * FF), a71 = *(const float4*)(xr0 + 7 * FF + 4);
    float4 h0  = *(const float4*)xh,             h1  = *(const float4*)(xh + 4);

    float sv[9];
#define DOT(p, q) (p.x * w0.x + p.y * w0.y + p.z * w0.z + p.w * w0.w \
                 + q.x * w1.x + q.y * w1.y + q.z * w1.z + q.w * w1.w)
    sv[0] = DOT(a00, a01);
    sv[1] = DOT(a10, a11);
    sv[2] = DOT(a20, a21);
    sv[3] = DOT(a30, a31);
    sv[4] = DOT(a40, a41);
    sv[5] = DOT(a50, a51);
    sv[6] = DOT(a60, a61);
    sv[7] = DOT(a70, a71);
    sv[8] = DOT(h0, h1);
#undef DOT

#pragma unroll
    for (int i = 0; i < 9; ++i) {
        float s = sv[i];
#pragma unroll
        for (int off = 32; off > 0; off >>= 1) s += __shfl_xor(s, off, 64);
        sv[i] = s;
    }

    if (lane == 0) {
#pragma unroll
        for (int i = 0; i < 8; ++i) {
            float val = 1.0f / (1.0f + expf(-(sv[i] + bz)));
            arr[1 + wv * 8 + i] = val;
            wt[rbase + i] = val;
        }
        if (wv == 0) arr[0]         = halo0 ? 1.0f / (1.0f + expf(-(sv[8] + bz))) : 0.f;
        if (wv == 3) arr[CHUNK + 1] = halo3 ? 1.0f / (1.0f + expf(-(sv[8] + bz))) : 0.f;
    }

    __syncthreads();

    // ---- valley flags for the 32 positions, wave 0 only ----
    if (tid < 64) {
        bool val = false;
        if (tid < CHUNK) {
            int t = t0 + tid;
            float cv = arr[1 + tid];
            float pv = arr[tid];
            float nv = arr[2 + tid];
            val = (t > 0) && (t < TT - 1) && (cv < pv) && (cv < nv);
        }
        unsigned long long bm = __ballot(val);
        if (tid == 0) flags[b * NCHUNK + c] = (unsigned int)bm;
    }
}

// K3: partitioned pool + zero + mask. Active waves reconstruct start/end from
// the 64 flag words of their batch (popc + wave scan + n-th set bit).
__global__ __launch_bounds__(256, 4) void pool_kernel(const float* __restrict__ x,
                                                      const float* __restrict__ wt,
                                                      const unsigned int* __restrict__ flags,
                                                      const int* __restrict__ seq_len,
                                                      float* __restrict__ out,
                                                      float* __restrict__ mask_out) {
    int blk = blockIdx.x;
    int tid = threadIdx.x;
    v4f zero = (v4f)(0.f);

    if (blk >= ACTIVE_UNITS + ZERO_UNITS) {
        // ---- mask: compute counts[b] for all b from flags, then new_mask ----
        __shared__ int cnts_lds[BB];
        int s4 = 0;
#pragma unroll
        for (int q = 0; q < 4; ++q) s4 += __popc(flags[tid * 4 + q]);
#pragma unroll
        for (int off = 1; off < 16; off <<= 1) s4 += __shfl_xor(s4, off, 64);
        if ((tid & 15) == 0) cnts_lds[tid >> 4] = s4 + 1;   // counts = #valleys + 1
        __syncthreads();
        int maxc = 0;
#pragma unroll
        for (int i = 0; i < BB; ++i) maxc = max(maxc, cnts_lds[i]);
        float len0 = (float)min(seq_len[0], TT);
        int idx = (blk - ACTIVE_UNITS - ZERO_UNITS) * 256 + tid;  // [0, 8192)
#pragma unroll
        for (int r = 0; r < 4; ++r) {
            int i = idx + r * 8192;       // [0, B*T)
            int b = i >> 11, t = i & (TT - 1);
            int nl = (int)((float)min(seq_len[b], TT) / len0 * (float)maxc);
            mask_out[i] = (t < nl) ? 1.0f : 0.0f;
        }
        return;
    }

    if (blk >= ACTIVE_UNITS) {
        // ---- zero region: rows j in [1024, 2048), 16 rows per block ----
        int zb = blk - ACTIVE_UNITS;      // [0, 1024)
        int b  = zb >> 6;
        int j0 = 1024 + (zb & 63) * 16;
        float* base = out + ((size_t)(b * TT + j0) * FF);
        v4f* dst = (v4f*)base + tid * 2;
        __builtin_nontemporal_store(zero, dst);
        __builtin_nontemporal_store(zero, dst + 1);
        return;
    }

    // ---- active pool: 4 waves/block, 1 wave per row, j in [0, 1024) ----
    int b    = blk >> 8;
    int wv   = tid >> 6;
    int lane = tid & 63;
    int j    = (blk & 255) * 4 + wv;
    int row  = b * TT + j;
    float* orow = out + (size_t)row * FF + lane * 8;

    // reconstruct segment boundaries from flags
    const unsigned int* fb = flags + b * NCHUNK;
    unsigned int wd = fb[lane];           // word `lane` covers t in [lane*32, lane*32+32)
    int pc  = __popc(wd);
    int inc = pc;
#pragma unroll
    for (int off = 1; off < 64; off <<= 1) {
        int y = __shfl_up(inc, off, 64);
        if (lane >= off) inc += y;
    }
    int exc = inc - pc;                   // exclusive prefix of set bits
    int k   = __shfl(inc, 63, 64);        // total #valleys
    int cnt = k + 1;

    v4f acc0 = zero;
    v4f acc1 = zero;
    if (j < cnt) {
        // j-th set bit (1-indexed) -> valley position
        auto findv = [&](int jj) -> int {
            bool has = (exc < jj) && (jj <= exc + pc);
            unsigned long long m = __ballot(has);
            int ls = (int)(__ffsll(m) - 1);
            unsigned int wsel = __shfl(wd, ls, 64);
            int base = __shfl(exc, ls, 64);
            int need = jj - base;         // in [1, 32]
            for (int q = 1; q < need; ++q) wsel &= wsel - 1;
            return ls * 32 + (__ffs(wsel) - 1);
        };
        int s = (j == 0) ? 0  : findv(j);
        int e = (j == k) ? TT : findv(j + 1) + 2;
        s = __builtin_amdgcn_readfirstlane(s);
        e = __builtin_amdgcn_readfirstlane(e);

        const float* xb   = x + (size_t)b * TT * FF + lane * 8;
        const float* wrow = wt + b * TT;
        float den = 0.f;
        for (int t = s; t < e; t += 4) {
            int i1 = (t + 1 < e) ? t + 1 : t;
            int i2 = (t + 2 < e) ? t + 2 : t;
            int i3 = (t + 3 < e) ? t + 3 : t;
            float w0 = wrow[t];
            float w1 = (t + 1 < e) ? wrow[i1] : 0.f;
            float w2 = (t + 2 < e) ? wrow[i2] : 0.f;
            float w3 = (t + 3 < e) ? wrow[i3] : 0.f;
            const v4f* p0 = (const v4f*)(xb + (size_t)t  * FF);
            const v4f* p1 = (const v4f*)(xb + (size_t)i1 * FF);
            const v4f* p2 = (const v4f*)(xb + (size_t)i2 * FF);
            const v4f* p3 = (const v4f*)(xb + (size_t)i3 * FF);
            v4f v00 = p0[0], v01 = p0[1];
            v4f v10 = p1[0], v11 = p1[1];
            v4f v20 = p2[0], v21 = p2[1];
            v4f v30 = p3[0], v31 = p3[1];
            acc0 += w0 * v00; acc1 += w0 * v01;
            acc0 += w1 * v10; acc1 += w1 * v11;
            acc0 += w2 * v20; acc1 += w2 * v21;
            acc0 += w3 * v30; acc1 += w3 * v31;
            den += w0 + w1 + w2 + w3;
        }
        float inv = 1.0f / fmaxf(den, 1e-6f);
        acc0 *= inv; acc1 *= inv;
    }
    __builtin_nontemporal_store(acc0, (v4f*)orow);
    __builtin_nontemporal_store(acc1, (v4f*)(orow + 4));
}

extern "C" void kernel_launch(void* const* d_in, const int* in_sizes, int n_in,
                              void* d_out, int out_size, void* d_ws, size_t ws_size,
                              hipStream_t stream) {
    const float* x       = (const float*)d_in[0];
    const float* w_aggr  = (const float*)d_in[1];
    const float* b_aggr  = (const float*)d_in[2];
    const int*   seq_len = (const int*)d_in[3];

    float* pooled = (float*)d_out;
    float* mask   = (float*)d_out + (size_t)BB * TT * FF;

    float*        wt    = (float*)d_ws;
    unsigned int* flags = (unsigned int*)((char*)d_ws + (size_t)BB * TT * 4);

    wtflag_kernel<<<BB * NCHUNK, 256, 0, stream>>>(x, w_aggr, b_aggr, wt, flags);
    pool_kernel<<<ACTIVE_UNITS + ZERO_UNITS + MASK_UNITS, 256, 0, stream>>>(
        x, wt, flags, seq_len, pooled, mask);
}